// Round 1
// baseline (4535.776 us; speedup 1.0000x reference)
//
#include <hip/hip_runtime.h>
#include <math.h>

// Problem constants (fixed by setup_inputs): B=32768 features, K=8192 centroids, D=384.
constexpr int B = 32768;
constexpr int K = 8192;
constexpr int D = 384;
constexpr float INV_T = 1.0f / 0.07f;

// ---------------------------------------------------------------------------
// Kernel 1: L2-normalize centroids. One wave (64 lanes) per row; D=384 -> 6
// scalar loads per lane, wave shuffle reduction, scale, write back.
// ---------------------------------------------------------------------------
__global__ __launch_bounds__(64) void normalize_k(const float* __restrict__ cent,
                                                  float* __restrict__ c) {
    const int row = blockIdx.x;
    const int lane = threadIdx.x;
    const float* src = cent + (size_t)row * D;
    float v[6];
    float ss = 0.f;
#pragma unroll
    for (int i = 0; i < 6; ++i) {
        v[i] = src[lane + 64 * i];
        ss += v[i] * v[i];
    }
#pragma unroll
    for (int off = 32; off > 0; off >>= 1) ss += __shfl_down(ss, off, 64);
    ss = __shfl(ss, 0, 64);
    const float inv = 1.0f / fmaxf(sqrtf(ss), 1e-12f);
    float* dst = c + (size_t)row * D;
#pragma unroll
    for (int i = 0; i < 6; ++i) dst[lane + 64 * i] = v[i] * inv;
}

// ---------------------------------------------------------------------------
// Kernel 2: cent_sum[j] = sum_i exp(c_i . c_j / T).
// 64x64 output tile per block, BK=16, 256 threads, 4x4 micro-tile.
// LDS tiles stored k-major, padded to 68 floats/row: fragment reads are
// ds_read_b128 with <=2-way bank aliasing (free), writes 2-way.
// Epilogue: exp + per-block column sum -> atomicAdd.
// ---------------------------------------------------------------------------
__global__ __launch_bounds__(256) void centsum_k(const float* __restrict__ c,
                                                 float* __restrict__ cent_sum) {
    __shared__ float As[16][68];
    __shared__ float Bs[16][68];
    __shared__ float red[16][64];
    const int tid = threadIdx.x;
    const int tx = tid & 15, ty = tid >> 4;
    const int lrow = tid >> 2;          // 0..63: tile row this thread stages
    const int lk4 = (tid & 3) * 4;      // 0,4,8,12: k-offset of its float4
    const int bi = blockIdx.x, bj = blockIdx.y;
    const float* aBase = c + (size_t)(bi * 64 + lrow) * D + lk4;
    const float* bBase = c + (size_t)(bj * 64 + lrow) * D + lk4;
    float acc[4][4] = {};
    for (int kc = 0; kc < D; kc += 16) {
        const float4 av = *(const float4*)(aBase + kc);
        const float4 bv = *(const float4*)(bBase + kc);
        __syncthreads();   // previous iteration's LDS reads complete
        As[lk4 + 0][lrow] = av.x; As[lk4 + 1][lrow] = av.y;
        As[lk4 + 2][lrow] = av.z; As[lk4 + 3][lrow] = av.w;
        Bs[lk4 + 0][lrow] = bv.x; Bs[lk4 + 1][lrow] = bv.y;
        Bs[lk4 + 2][lrow] = bv.z; Bs[lk4 + 3][lrow] = bv.w;
        __syncthreads();
#pragma unroll
        for (int kk = 0; kk < 16; ++kk) {
            const float4 a4 = *(const float4*)&As[kk][ty * 4];
            const float4 b4 = *(const float4*)&Bs[kk][tx * 4];
            const float aa[4] = {a4.x, a4.y, a4.z, a4.w};
            const float bb[4] = {b4.x, b4.y, b4.z, b4.w};
#pragma unroll
            for (int i = 0; i < 4; ++i)
#pragma unroll
                for (int j = 0; j < 4; ++j)
                    acc[i][j] = fmaf(aa[i], bb[j], acc[i][j]);
        }
    }
    // Epilogue: per-thread sum of exp over its 4 rows, per column.
#pragma unroll
    for (int j = 0; j < 4; ++j) {
        float s = 0.f;
#pragma unroll
        for (int i = 0; i < 4; ++i) s += expf(acc[i][j] * INV_T);
        red[ty][tx * 4 + j] = s;   // overwritten below after sync barrier... per j
    }
    // NOTE: red[ty][col] holds this thread's partial for its 4 columns.
    __syncthreads();
    if (ty == 0) {
#pragma unroll
        for (int j = 0; j < 4; ++j) {
            float s = 0.f;
            for (int t = 0; t < 16; ++t) s += red[t][tx * 4 + j];
            atomicAdd(&cent_sum[bj * 64 + tx * 4 + j], s);
        }
    }
}

// ---------------------------------------------------------------------------
// Kernel 3: per-feature-row max + argmax over all K centroids.
// Block = 64 feature rows; loops over 128 centroid tiles of 64.
// Same GEMM micro-structure as centsum_k; epilogue keeps running
// (max, argmax) per thread-row, then cross-thread (tx) reduce via LDS.
// Tie-break: lowest global centroid index (matches jnp.argmax).
// ---------------------------------------------------------------------------
__global__ __launch_bounds__(256) void rowmax_k(const float* __restrict__ f,
                                                const float* __restrict__ c,
                                                float* __restrict__ row_max,
                                                int* __restrict__ row_arg) {
    __shared__ float As[16][68];
    __shared__ float Bs[16][68];
    __shared__ float rv[16][64];
    __shared__ int   ri[16][64];
    const int tid = threadIdx.x;
    const int tx = tid & 15, ty = tid >> 4;
    const int lrow = tid >> 2;
    const int lk4 = (tid & 3) * 4;
    const int bm = blockIdx.x;
    const float* aBase = f + (size_t)(bm * 64 + lrow) * D + lk4;
    float bestv[4] = {-INFINITY, -INFINITY, -INFINITY, -INFINITY};
    int besti[4] = {0, 0, 0, 0};
    for (int ct = 0; ct < K / 64; ++ct) {
        const float* bBase = c + (size_t)(ct * 64 + lrow) * D + lk4;
        float acc[4][4] = {};
        for (int kc = 0; kc < D; kc += 16) {
            const float4 av = *(const float4*)(aBase + kc);
            const float4 bv = *(const float4*)(bBase + kc);
            __syncthreads();
            As[lk4 + 0][lrow] = av.x; As[lk4 + 1][lrow] = av.y;
            As[lk4 + 2][lrow] = av.z; As[lk4 + 3][lrow] = av.w;
            Bs[lk4 + 0][lrow] = bv.x; Bs[lk4 + 1][lrow] = bv.y;
            Bs[lk4 + 2][lrow] = bv.z; Bs[lk4 + 3][lrow] = bv.w;
            __syncthreads();
#pragma unroll
            for (int kk = 0; kk < 16; ++kk) {
                const float4 a4 = *(const float4*)&As[kk][ty * 4];
                const float4 b4 = *(const float4*)&Bs[kk][tx * 4];
                const float aa[4] = {a4.x, a4.y, a4.z, a4.w};
                const float bb[4] = {b4.x, b4.y, b4.z, b4.w};
#pragma unroll
                for (int i = 0; i < 4; ++i)
#pragma unroll
                    for (int j = 0; j < 4; ++j)
                        acc[i][j] = fmaf(aa[i], bb[j], acc[i][j]);
            }
        }
        // Running max/argmax. Strict '>' keeps the lowest index on ties
        // (columns are visited in increasing global-index order per thread).
#pragma unroll
        for (int i = 0; i < 4; ++i)
#pragma unroll
            for (int j = 0; j < 4; ++j) {
                const float v = acc[i][j];
                if (v > bestv[i]) { bestv[i] = v; besti[i] = ct * 64 + tx * 4 + j; }
            }
    }
#pragma unroll
    for (int i = 0; i < 4; ++i) {
        rv[tx][ty * 4 + i] = bestv[i];
        ri[tx][ty * 4 + i] = besti[i];
    }
    __syncthreads();
    if (tid < 64) {
        float bv = -INFINITY;
        int bx = 0x7fffffff;
        for (int t = 0; t < 16; ++t) {
            const float v = rv[t][tid];
            const int ix = ri[t][tid];
            if (v > bv || (v == bv && ix < bx)) { bv = v; bx = ix; }
        }
        row_max[bm * 64 + tid] = bv;
        row_arg[bm * 64 + tid] = bx;
    }
}

// ---------------------------------------------------------------------------
// Kernel 4: loss = mean_b log1p(cent_sum[arg_b] * exp(-max_b / T)).
// Single block; gather on cent_sum (32 KB, L2-resident).
// ---------------------------------------------------------------------------
__global__ __launch_bounds__(256) void loss_k(const float* __restrict__ row_max,
                                              const int* __restrict__ row_arg,
                                              const float* __restrict__ cent_sum,
                                              float* __restrict__ out) {
    __shared__ float red[256];
    const int tid = threadIdx.x;
    float s = 0.f;
    for (int b = tid; b < B; b += 256) {
        const float m = row_max[b];
        const float cs = cent_sum[row_arg[b]];
        s += log1pf(cs * expf(-m * INV_T));
    }
    red[tid] = s;
    __syncthreads();
    for (int off = 128; off > 0; off >>= 1) {
        if (tid < off) red[tid] += red[tid + off];
        __syncthreads();
    }
    if (tid == 0) out[0] = red[0] / (float)B;
}

extern "C" void kernel_launch(void* const* d_in, const int* in_sizes, int n_in,
                              void* d_out, int out_size, void* d_ws, size_t ws_size,
                              hipStream_t stream) {
    const float* features  = (const float*)d_in[0];   // [B, D] fp32, L2-normalized
    const float* centroids = (const float*)d_in[1];   // [K, D] fp32
    float* out = (float*)d_out;                       // scalar fp32

    char* ws = (char*)d_ws;
    float* c        = (float*)ws;                             // K*D fp32 (12.6 MB)
    float* cent_sum = (float*)(ws + (size_t)K * D * sizeof(float)); // K fp32
    float* row_max  = cent_sum + K;                           // B fp32
    int*   row_arg  = (int*)(row_max + B);                    // B int32

    hipMemsetAsync(cent_sum, 0, K * sizeof(float), stream);
    normalize_k<<<K, 64, 0, stream>>>(centroids, c);
    centsum_k<<<dim3(K / 64, K / 64), 256, 0, stream>>>(c, cent_sum);
    rowmax_k<<<B / 64, 256, 0, stream>>>(features, c, row_max, row_arg);
    loss_k<<<1, 256, 0, stream>>>(row_max, row_arg, cent_sum, out);
}

// Round 2
// 1398.456 us; speedup vs baseline: 3.2434x; 3.2434x over previous
//
#include <hip/hip_runtime.h>
#include <math.h>

// B=32768 features, K=8192 centroids, D=384. All fixed by setup_inputs.
constexpr int B = 32768;
constexpr int K = 8192;
constexpr int D = 384;
constexpr float INV_T = 1.0f / 0.07f;

typedef short  short8   __attribute__((ext_vector_type(8)));
typedef float  floatx16 __attribute__((ext_vector_type(16)));

// LDS centroid tile: 64 rows x 392 bf16 (pad 384->392 breaks the 768B-stride
// bank pathology; rows stay 16B-aligned: 392*2=784=49*16).
constexpr int LDSN = 392;

// fp32 -> bf16 round-to-nearest-even
__device__ __forceinline__ unsigned short f2bf(float f) {
    unsigned int u = __float_as_uint(f);
    u = (u + 0x7fffu + ((u >> 16) & 1u)) >> 16;
    return (unsigned short)u;
}

// ---------------------------------------------------------------------------
// Kernel 1: L2-normalize centroids -> bf16 cb[K*D].
// ---------------------------------------------------------------------------
__global__ __launch_bounds__(64) void normalize_k(const float* __restrict__ cent,
                                                  unsigned short* __restrict__ cb) {
    const int row = blockIdx.x, lane = threadIdx.x;
    const float* src = cent + (size_t)row * D;
    float v[6];
    float ss = 0.f;
#pragma unroll
    for (int i = 0; i < 6; ++i) { v[i] = src[lane + 64 * i]; ss += v[i] * v[i]; }
#pragma unroll
    for (int off = 32; off > 0; off >>= 1) ss += __shfl_down(ss, off, 64);
    ss = __shfl(ss, 0, 64);
    const float inv = 1.0f / fmaxf(sqrtf(ss), 1e-12f);
    unsigned short* dst = cb + (size_t)row * D;
#pragma unroll
    for (int i = 0; i < 6; ++i) dst[lane + 64 * i] = f2bf(v[i] * inv);
}

// ---------------------------------------------------------------------------
// Shared staging: 256 threads stage a 64x384 bf16 centroid tile into padded LDS.
// Chunk g in [0,3072): row g/48, col-chunk g%48 (16B chunks).
// ---------------------------------------------------------------------------
__device__ __forceinline__ void stage_tile(const unsigned short* __restrict__ gsrc,
                                           unsigned short* __restrict__ bs, int tid) {
    uint4 v[12];
    const char* g = (const char*)gsrc;
#pragma unroll
    for (int i = 0; i < 12; ++i)
        v[i] = *(const uint4*)(g + i * 4096 + tid * 16);
    __syncthreads();  // prior iteration's LDS reads done
#pragma unroll
    for (int i = 0; i < 12; ++i) {
        const int gidx = i * 256 + tid;
        const int r = gidx / 48, c = gidx % 48;
        *(uint4*)((char*)bs + r * (LDSN * 2) + c * 16) = v[i];
    }
    __syncthreads();
}

// ---------------------------------------------------------------------------
// Kernel 2: cent_sum[j] = sum_i exp(c_j . c_i / T)  (symmetric -> row sums).
// Grid (K/64, 2): 64 centroid rows per block, half the col-tiles per y-slice.
// ---------------------------------------------------------------------------
__global__ __launch_bounds__(256) void centsum_k(const unsigned short* __restrict__ cb,
                                                 float* __restrict__ cent_sum) {
    __shared__ unsigned short bs[64 * LDSN];
    const int tid = threadIdx.x, lane = tid & 63, wave = tid >> 6;
    const int wm = wave >> 1, wn = wave & 1;
    const int l31 = lane & 31, half = lane >> 5;

    // Resident A: this wave's 32 centroid rows, full depth (24 frags).
    short8 afr[24];
    const unsigned short* arow = cb + ((size_t)blockIdx.x * 64 + wm * 32 + l31) * D;
#pragma unroll
    for (int t = 0; t < 24; ++t)
        afr[t] = *(const short8*)(arow + t * 16 + half * 8);

    float rs[16];
#pragma unroll
    for (int r = 0; r < 16; ++r) rs[r] = 0.f;

    const int ct0 = (blockIdx.x & 7) * 8;
    for (int it = 0; it < 64; ++it) {
        const int ct = blockIdx.y * 64 + ((ct0 + it) & 63);
        stage_tile(cb + (size_t)ct * 64 * D, bs, tid);

        floatx16 acc;
#pragma unroll
        for (int r = 0; r < 16; ++r) acc[r] = 0.f;
        const char* bbase = (const char*)bs + (size_t)(wn * 32 + l31) * (LDSN * 2) + half * 16;
#pragma unroll
        for (int t = 0; t < 24; ++t) {
            const short8 bfr = *(const short8*)(bbase + t * 32);
            acc = __builtin_amdgcn_mfma_f32_32x32x16_bf16(afr[t], bfr, acc, 0, 0, 0);
        }
#pragma unroll
        for (int r = 0; r < 16; ++r) rs[r] += __expf(acc[r] * INV_T);
    }

    // Reduce over the 32 col-lanes of each half; lanes 0/32 own the row partial.
#pragma unroll
    for (int r = 0; r < 16; ++r) {
        float s = rs[r];
#pragma unroll
        for (int off = 1; off < 32; off <<= 1) s += __shfl_xor(s, off, 64);
        if (l31 == 0) {
            const int rowl = (r & 3) + 8 * (r >> 2) + 4 * half;
            atomicAdd(&cent_sum[blockIdx.x * 64 + wm * 32 + rowl], s);
        }
    }
}

// ---------------------------------------------------------------------------
// Kernel 3: per-feature-row max+argmax over all K centroids. 512 blocks x 64 rows.
// ---------------------------------------------------------------------------
__global__ __launch_bounds__(256) void rowmax_k(const float* __restrict__ f,
                                                const unsigned short* __restrict__ cb,
                                                float* __restrict__ row_max,
                                                int* __restrict__ row_arg) {
    __shared__ unsigned short bs[64 * LDSN];
    const int tid = threadIdx.x, lane = tid & 63, wave = tid >> 6;
    const int wm = wave >> 1, wn = wave & 1;
    const int l31 = lane & 31, half = lane >> 5;

    // Resident A: 32 feature rows, fp32->bf16 in-register (used by this block only).
    short8 afr[24];
    const float* arow = f + ((size_t)blockIdx.x * 64 + wm * 32 + l31) * D;
#pragma unroll
    for (int t = 0; t < 24; ++t) {
        const int k0 = t * 16 + half * 8;
        const float4 x = *(const float4*)(arow + k0);
        const float4 y = *(const float4*)(arow + k0 + 4);
        short8 a;
        a[0] = (short)f2bf(x.x); a[1] = (short)f2bf(x.y);
        a[2] = (short)f2bf(x.z); a[3] = (short)f2bf(x.w);
        a[4] = (short)f2bf(y.x); a[5] = (short)f2bf(y.y);
        a[6] = (short)f2bf(y.z); a[7] = (short)f2bf(y.w);
        afr[t] = a;
    }

    float bestv[16];
    int   besti[16];
#pragma unroll
    for (int r = 0; r < 16; ++r) { bestv[r] = -INFINITY; besti[r] = 0; }

    const int ct0 = (blockIdx.x & 7) * 16;
    for (int it = 0; it < K / 64; ++it) {
        const int ct = (ct0 + it) & (K / 64 - 1);
        stage_tile(cb + (size_t)ct * 64 * D, bs, tid);

        floatx16 acc;
#pragma unroll
        for (int r = 0; r < 16; ++r) acc[r] = 0.f;
        const char* bbase = (const char*)bs + (size_t)(wn * 32 + l31) * (LDSN * 2) + half * 16;
#pragma unroll
        for (int t = 0; t < 24; ++t) {
            const short8 bfr = *(const short8*)(bbase + t * 32);
            acc = __builtin_amdgcn_mfma_f32_32x32x16_bf16(afr[t], bfr, acc, 0, 0, 0);
        }
        const int curCol = ct * 64 + wn * 32 + l31;
#pragma unroll
        for (int r = 0; r < 16; ++r) {
            const float v = acc[r];
            if (v > bestv[r]) { bestv[r] = v; besti[r] = curCol; }
        }
    }

    // Cross-lane (col) reduce with low-index tie-break; halves are distinct rows.
#pragma unroll
    for (int r = 0; r < 16; ++r) {
        float v = bestv[r]; int ix = besti[r];
#pragma unroll
        for (int off = 1; off < 32; off <<= 1) {
            const float ov = __shfl_xor(v, off, 64);
            const int   oi = __shfl_xor(ix, off, 64);
            if (ov > v || (ov == v && oi < ix)) { v = ov; ix = oi; }
        }
        bestv[r] = v; besti[r] = ix;
    }

    __syncthreads();  // done with bs as a tile; reuse for cross-wave reduce
    float* rv = (float*)bs;        // [64][2]
    int*   ri = (int*)bs + 128;    // [64][2]
    if (l31 == 0) {
#pragma unroll
        for (int r = 0; r < 16; ++r) {
            const int rowl = wm * 32 + (r & 3) + 8 * (r >> 2) + 4 * half;
            rv[rowl * 2 + wn] = bestv[r];
            ri[rowl * 2 + wn] = besti[r];
        }
    }
    __syncthreads();
    if (tid < 64) {
        const float v0 = rv[tid * 2], v1 = rv[tid * 2 + 1];
        const int   i0 = ri[tid * 2], i1 = ri[tid * 2 + 1];
        const bool take1 = (v1 > v0) || (v1 == v0 && i1 < i0);
        row_max[blockIdx.x * 64 + tid] = take1 ? v1 : v0;
        row_arg[blockIdx.x * 64 + tid] = take1 ? i1 : i0;
    }
}

// ---------------------------------------------------------------------------
// Kernel 4: loss = mean_b log1p(cent_sum[arg_b] * exp(-max_b / T)).
// ---------------------------------------------------------------------------
__global__ __launch_bounds__(256) void loss_k(const float* __restrict__ row_max,
                                              const int* __restrict__ row_arg,
                                              const float* __restrict__ cent_sum,
                                              float* __restrict__ out) {
    __shared__ float red[256];
    const int tid = threadIdx.x;
    float s = 0.f;
    for (int b = tid; b < B; b += 256) {
        const float m = row_max[b];
        const float cs = cent_sum[row_arg[b]];
        s += log1pf(cs * expf(-m * INV_T));
    }
    red[tid] = s;
    __syncthreads();
    for (int off = 128; off > 0; off >>= 1) {
        if (tid < off) red[tid] += red[tid + off];
        __syncthreads();
    }
    if (tid == 0) out[0] = red[0] / (float)B;
}

extern "C" void kernel_launch(void* const* d_in, const int* in_sizes, int n_in,
                              void* d_out, int out_size, void* d_ws, size_t ws_size,
                              hipStream_t stream) {
    const float* features  = (const float*)d_in[0];   // [B, D] fp32
    const float* centroids = (const float*)d_in[1];   // [K, D] fp32
    float* out = (float*)d_out;

    char* ws = (char*)d_ws;
    unsigned short* cb = (unsigned short*)ws;                       // K*D bf16 (6.3 MB)
    float* cent_sum = (float*)(ws + (size_t)K * D * sizeof(unsigned short));
    float* row_max  = cent_sum + K;
    int*   row_arg  = (int*)(row_max + B);

    hipMemsetAsync(cent_sum, 0, K * sizeof(float), stream);
    normalize_k<<<K, 64, 0, stream>>>(centroids, cb);
    centsum_k<<<dim3(K / 64, 2), 256, 0, stream>>>(cb, cent_sum);
    rowmax_k<<<B / 64, 256, 0, stream>>>(features, cb, row_max, row_arg);
    loss_k<<<1, 256, 0, stream>>>(row_max, row_arg, cent_sum, out);
}

// Round 3
// 823.508 us; speedup vs baseline: 5.5079x; 1.6982x over previous
//
#include <hip/hip_runtime.h>
#include <math.h>

// B=32768 features, K=8192 centroids, D=384. All fixed by setup_inputs.
constexpr int B = 32768;
constexpr int K = 8192;
constexpr int D = 384;
constexpr float INV_T = 1.0f / 0.07f;

typedef short  short8   __attribute__((ext_vector_type(8)));
typedef float  floatx16 __attribute__((ext_vector_type(16)));

// fp32 -> bf16 round-to-nearest-even
__device__ __forceinline__ unsigned short f2bf(float f) {
    unsigned int u = __float_as_uint(f);
    u = (u + 0x7fffu + ((u >> 16) & 1u)) >> 16;
    return (unsigned short)u;
}

// ---------------------------------------------------------------------------
// Kernel 1: L2-normalize centroids -> bf16 cb[K*D].
// ---------------------------------------------------------------------------
__global__ __launch_bounds__(64) void normalize_k(const float* __restrict__ cent,
                                                  unsigned short* __restrict__ cb) {
    const int row = blockIdx.x, lane = threadIdx.x;
    const float* src = cent + (size_t)row * D;
    float v[6];
    float ss = 0.f;
#pragma unroll
    for (int i = 0; i < 6; ++i) { v[i] = src[lane + 64 * i]; ss += v[i] * v[i]; }
#pragma unroll
    for (int off = 32; off > 0; off >>= 1) ss += __shfl_down(ss, off, 64);
    ss = __shfl(ss, 0, 64);
    const float inv = 1.0f / fmaxf(sqrtf(ss), 1e-12f);
    unsigned short* dst = cb + (size_t)row * D;
#pragma unroll
    for (int i = 0; i < 6; ++i) dst[lane + 64 * i] = f2bf(v[i] * inv);
}

// ---------------------------------------------------------------------------
// Async staging of a 64x384 bf16 tile into LDS, chunk-column layout:
// 16-B chunk c (0..47) of row r (0..63) lives at bs + (c*64 + r)*16.
// global_load_lds writes wave-uniform base + lane*16: lane l supplies row l.
// Wave w stages chunk-columns w*12 .. w*12+11 (lane l reads 192 contiguous
// bytes of row l -> full 64B-line utilization in L1/L2).
// No VGPR round-trip: this is what kills the R2 spill storm.
// ---------------------------------------------------------------------------
__device__ __forceinline__ void stage_tile_async(const unsigned short* __restrict__ gsrc,
                                                 unsigned short* __restrict__ bs,
                                                 int wave, int lane) {
    const char* g = (const char*)gsrc + (size_t)lane * (D * 2) + wave * 192;
    char* l = (char*)bs + wave * 12 * 1024;
#pragma unroll
    for (int i = 0; i < 12; ++i) {
        __builtin_amdgcn_global_load_lds(
            (const __attribute__((address_space(1))) unsigned int*)(g + i * 16),
            (__attribute__((address_space(3))) unsigned int*)(l + i * 1024),
            16, 0, 0);
    }
}

// B-fragment read in chunk-column layout: frag (t, half) of col row cr is at
// (2t+half)*1024 + cr*16 -- contiguous across lanes => conflict-free b128.

// ---------------------------------------------------------------------------
// Kernel 2: cent_sum[j] = sum_i exp(c_j . c_i / T)  (symmetric -> row sums).
// Grid (K/64, 2): 64 centroid rows per block, half the col-tiles per y-slice.
// ---------------------------------------------------------------------------
__global__ __launch_bounds__(256, 2) void centsum_k(const unsigned short* __restrict__ cb,
                                                    float* __restrict__ cent_sum) {
    __shared__ unsigned short bs[64 * D];   // 48 KB, chunk-column layout
    const int tid = threadIdx.x, lane = tid & 63, wave = tid >> 6;
    const int wm = wave >> 1, wn = wave & 1;
    const int l31 = lane & 31, half = lane >> 5;

    // Resident A: this wave's 32 centroid rows, full depth (24 frags, 96 VGPRs).
    short8 afr[24];
    const unsigned short* arow = cb + ((size_t)blockIdx.x * 64 + wm * 32 + l31) * D;
#pragma unroll
    for (int t = 0; t < 24; ++t)
        afr[t] = *(const short8*)(arow + t * 16 + half * 8);

    float rs[16];
#pragma unroll
    for (int r = 0; r < 16; ++r) rs[r] = 0.f;

    const int ct0 = (blockIdx.x & 7) * 8;   // per-XCD stagger; same-XCD blocks aligned
    for (int it = 0; it < 64; ++it) {
        const int ct = blockIdx.y * 64 + ((ct0 + it) & 63);
        __syncthreads();   // prior tile's LDS reads complete
        stage_tile_async(cb + (size_t)ct * 64 * D, bs, wave, lane);
        __syncthreads();   // drains vmcnt(0): staged tile visible

        floatx16 acc;
#pragma unroll
        for (int r = 0; r < 16; ++r) acc[r] = 0.f;
        const char* bbase = (const char*)bs + (wn * 32 + l31) * 16 + half * 1024;
#pragma unroll
        for (int t = 0; t < 24; ++t) {
            const short8 bfr = *(const short8*)(bbase + t * 2048);
            acc = __builtin_amdgcn_mfma_f32_32x32x16_bf16(afr[t], bfr, acc, 0, 0, 0);
        }
#pragma unroll
        for (int r = 0; r < 16; ++r) rs[r] += __expf(acc[r] * INV_T);
    }

    // Reduce over the 32 col-lanes of each half; lanes 0/32 own the row partial.
#pragma unroll
    for (int r = 0; r < 16; ++r) {
        float s = rs[r];
#pragma unroll
        for (int off = 1; off < 32; off <<= 1) s += __shfl_xor(s, off, 64);
        if (l31 == 0) {
            const int rowl = (r & 3) + 8 * (r >> 2) + 4 * half;
            atomicAdd(&cent_sum[blockIdx.x * 64 + wm * 32 + rowl], s);
        }
    }
}

// ---------------------------------------------------------------------------
// Kernel 3: per-feature-row max+argmax over all K centroids. 512 blocks x 64 rows.
// ---------------------------------------------------------------------------
__global__ __launch_bounds__(256, 2) void rowmax_k(const float* __restrict__ f,
                                                   const unsigned short* __restrict__ cb,
                                                   float* __restrict__ row_max,
                                                   int* __restrict__ row_arg) {
    __shared__ unsigned short bs[64 * D];   // 48 KB, chunk-column layout
    const int tid = threadIdx.x, lane = tid & 63, wave = tid >> 6;
    const int wm = wave >> 1, wn = wave & 1;
    const int l31 = lane & 31, half = lane >> 5;

    // Resident A: 32 feature rows, fp32->bf16 in-register (used by this block only).
    short8 afr[24];
    const float* arow = f + ((size_t)blockIdx.x * 64 + wm * 32 + l31) * D;
#pragma unroll
    for (int t = 0; t < 24; ++t) {
        const int k0 = t * 16 + half * 8;
        const float4 x = *(const float4*)(arow + k0);
        const float4 y = *(const float4*)(arow + k0 + 4);
        short8 a;
        a[0] = (short)f2bf(x.x); a[1] = (short)f2bf(x.y);
        a[2] = (short)f2bf(x.z); a[3] = (short)f2bf(x.w);
        a[4] = (short)f2bf(y.x); a[5] = (short)f2bf(y.y);
        a[6] = (short)f2bf(y.z); a[7] = (short)f2bf(y.w);
        afr[t] = a;
    }

    float bestv[16];
    int   besti[16];
#pragma unroll
    for (int r = 0; r < 16; ++r) { bestv[r] = -INFINITY; besti[r] = 0; }

    const int ct0 = (blockIdx.x & 7) * 16;  // per-XCD stagger
    for (int it = 0; it < K / 64; ++it) {
        const int ct = (ct0 + it) & (K / 64 - 1);
        __syncthreads();
        stage_tile_async(cb + (size_t)ct * 64 * D, bs, wave, lane);
        __syncthreads();

        floatx16 acc;
#pragma unroll
        for (int r = 0; r < 16; ++r) acc[r] = 0.f;
        const char* bbase = (const char*)bs + (wn * 32 + l31) * 16 + half * 1024;
#pragma unroll
        for (int t = 0; t < 24; ++t) {
            const short8 bfr = *(const short8*)(bbase + t * 2048);
            acc = __builtin_amdgcn_mfma_f32_32x32x16_bf16(afr[t], bfr, acc, 0, 0, 0);
        }
        const int curCol = ct * 64 + wn * 32 + l31;
#pragma unroll
        for (int r = 0; r < 16; ++r) {
            const float v = acc[r];
            if (v > bestv[r]) { bestv[r] = v; besti[r] = curCol; }
        }
    }

    // Cross-lane (col) reduce with low-index tie-break; halves are distinct rows.
#pragma unroll
    for (int r = 0; r < 16; ++r) {
        float v = bestv[r]; int ix = besti[r];
#pragma unroll
        for (int off = 1; off < 32; off <<= 1) {
            const float ov = __shfl_xor(v, off, 64);
            const int   oi = __shfl_xor(ix, off, 64);
            if (ov > v || (ov == v && oi < ix)) { v = ov; ix = oi; }
        }
        bestv[r] = v; besti[r] = ix;
    }

    __syncthreads();  // done with bs as a tile; reuse for cross-wave reduce
    float* rv = (float*)bs;        // [64][2]
    int*   ri = (int*)bs + 128;    // [64][2]
    if (l31 == 0) {
#pragma unroll
        for (int r = 0; r < 16; ++r) {
            const int rowl = wm * 32 + (r & 3) + 8 * (r >> 2) + 4 * half;
            rv[rowl * 2 + wn] = bestv[r];
            ri[rowl * 2 + wn] = besti[r];
        }
    }
    __syncthreads();
    if (tid < 64) {
        const float v0 = rv[tid * 2], v1 = rv[tid * 2 + 1];
        const int   i0 = ri[tid * 2], i1 = ri[tid * 2 + 1];
        const bool take1 = (v1 > v0) || (v1 == v0 && i1 < i0);
        row_max[blockIdx.x * 64 + tid] = take1 ? v1 : v0;
        row_arg[blockIdx.x * 64 + tid] = take1 ? i1 : i0;
    }
}

// ---------------------------------------------------------------------------
// Kernel 4: loss = mean_b log1p(cent_sum[arg_b] * exp(-max_b / T)).
// 32 blocks, per-block partial -> atomicAdd (out pre-zeroed by memsetAsync).
// ---------------------------------------------------------------------------
__global__ __launch_bounds__(256) void loss_k(const float* __restrict__ row_max,
                                              const int* __restrict__ row_arg,
                                              const float* __restrict__ cent_sum,
                                              float* __restrict__ out) {
    __shared__ float red[256];
    const int tid = threadIdx.x;
    float s = 0.f;
    for (int b = blockIdx.x * 256 + tid; b < B; b += gridDim.x * 256) {
        const float m = row_max[b];
        const float cs = cent_sum[row_arg[b]];
        s += log1pf(cs * expf(-m * INV_T));
    }
    red[tid] = s;
    __syncthreads();
    for (int off = 128; off > 0; off >>= 1) {
        if (tid < off) red[tid] += red[tid + off];
        __syncthreads();
    }
    if (tid == 0) atomicAdd(out, red[0] / (float)B);
}

extern "C" void kernel_launch(void* const* d_in, const int* in_sizes, int n_in,
                              void* d_out, int out_size, void* d_ws, size_t ws_size,
                              hipStream_t stream) {
    const float* features  = (const float*)d_in[0];   // [B, D] fp32
    const float* centroids = (const float*)d_in[1];   // [K, D] fp32
    float* out = (float*)d_out;

    char* ws = (char*)d_ws;
    unsigned short* cb = (unsigned short*)ws;                       // K*D bf16 (6.3 MB)
    float* cent_sum = (float*)(ws + (size_t)K * D * sizeof(unsigned short));
    float* row_max  = cent_sum + K;
    int*   row_arg  = (int*)(row_max + B);

    hipMemsetAsync(cent_sum, 0, K * sizeof(float), stream);
    hipMemsetAsync(out, 0, sizeof(float), stream);
    normalize_k<<<K, 64, 0, stream>>>(centroids, cb);
    centsum_k<<<dim3(K / 64, 2), 256, 0, stream>>>(cb, cent_sum);
    rowmax_k<<<B / 64, 256, 0, stream>>>(features, cb, row_max, row_arg);
    loss_k<<<32, 256, 0, stream>>>(row_max, row_arg, cent_sum, out);
}

// Round 4
// 427.637 us; speedup vs baseline: 10.6066x; 1.9257x over previous
//
#include <hip/hip_runtime.h>
#include <math.h>

// B=32768 features, K=8192 centroids, D=384. All fixed by setup_inputs.
constexpr int B = 32768;
constexpr int K = 8192;
constexpr int D = 384;
constexpr float INV_T = 1.0f / 0.07f;

// Swizzled centroid buffer: per 64-row tile t (128 tiles), chunk-column layout:
// 16-B chunk c (0..47) of row r (0..63) at cbs + t*49152 + (c*64 + r)*16.
// This is byte-identical to the LDS tile layout, so staging is a straight
// coalesced copy (1 KB/instruction) and fragment addressing is shared.
constexpr int TILE_BYTES = 48 * 64 * 16;   // 49152

typedef short  short8   __attribute__((ext_vector_type(8)));
typedef float  floatx16 __attribute__((ext_vector_type(16)));

// fp32 -> bf16 round-to-nearest-even
__device__ __forceinline__ unsigned short f2bf(float f) {
    unsigned int u = __float_as_uint(f);
    u = (u + 0x7fffu + ((u >> 16) & 1u)) >> 16;
    return (unsigned short)u;
}

// ---------------------------------------------------------------------------
// Kernel 1: L2-normalize centroids -> bf16, written directly in swizzled
// tile layout. One 64-lane wave per row; lanes 0..47 each own one 16B chunk.
// ---------------------------------------------------------------------------
__global__ __launch_bounds__(64) void normalize_k(const float* __restrict__ cent,
                                                  unsigned short* __restrict__ cbs) {
    const int row = blockIdx.x, lane = threadIdx.x;
    const float* src = cent + (size_t)row * D;
    float4 x = {0.f, 0.f, 0.f, 0.f}, y = {0.f, 0.f, 0.f, 0.f};
    if (lane < 48) {
        x = *(const float4*)(src + lane * 8);
        y = *(const float4*)(src + lane * 8 + 4);
    }
    float ss = x.x * x.x + x.y * x.y + x.z * x.z + x.w * x.w
             + y.x * y.x + y.y * y.y + y.z * y.z + y.w * y.w;
#pragma unroll
    for (int off = 32; off > 0; off >>= 1) ss += __shfl_down(ss, off, 64);
    ss = __shfl(ss, 0, 64);
    const float inv = 1.0f / fmaxf(sqrtf(ss), 1e-12f);
    if (lane < 48) {
        short8 o;
        o[0] = (short)f2bf(x.x * inv); o[1] = (short)f2bf(x.y * inv);
        o[2] = (short)f2bf(x.z * inv); o[3] = (short)f2bf(x.w * inv);
        o[4] = (short)f2bf(y.x * inv); o[5] = (short)f2bf(y.y * inv);
        o[6] = (short)f2bf(y.z * inv); o[7] = (short)f2bf(y.w * inv);
        char* dst = (char*)cbs + (size_t)(row >> 6) * TILE_BYTES
                  + ((size_t)lane * 64 + (row & 63)) * 16;
        *(short8*)dst = o;
    }
}

// ---------------------------------------------------------------------------
// Async staging of one swizzled 48KB tile into LDS: wave w copies bytes
// [w*12KB, (w+1)*12KB), 1KB (64 lanes x 16B contiguous) per instruction.
// ---------------------------------------------------------------------------
__device__ __forceinline__ void stage_tile_async(const char* __restrict__ gtile,
                                                 char* __restrict__ bs,
                                                 int wave, int lane) {
    const char* g = gtile + wave * 12 * 1024 + lane * 16;
    char* l = bs + wave * 12 * 1024;
#pragma unroll
    for (int i = 0; i < 12; ++i) {
        __builtin_amdgcn_global_load_lds(
            (const __attribute__((address_space(1))) unsigned int*)(g + i * 1024),
            (__attribute__((address_space(3))) unsigned int*)(l + i * 1024),
            16, 0, 0);
    }
}

// Fragment read (global swizzled or LDS tile): frag (t24, half) of row r is at
// base + (2*t24+half)*1024 + r*16 -- contiguous across lanes => conflict-free.

// ---------------------------------------------------------------------------
// Kernel 2: cent_sum[j] = sum_i exp(c_j . c_i / T)  (symmetric -> row sums).
// Grid (K/64, 2): 64 centroid rows per block, half the col-tiles per y-slice.
// ---------------------------------------------------------------------------
__global__ __launch_bounds__(256, 3) void centsum_k(const unsigned short* __restrict__ cbs,
                                                    float* __restrict__ cent_sum) {
    __shared__ unsigned short bs[64 * D];   // 48 KB, chunk-column layout
    const int tid = threadIdx.x, lane = tid & 63, wave = tid >> 6;
    const int wm = wave >> 1, wn = wave & 1;
    const int l31 = lane & 31, half = lane >> 5;

    // Resident A: this wave's 32 centroid rows from the swizzled buffer
    // (24 frags, 96 VGPRs). Coalesced: each half-wave reads 512B runs.
    short8 afr[24];
    const char* abase = (const char*)cbs + (size_t)blockIdx.x * TILE_BYTES
                      + (wm * 32 + l31) * 16 + half * 1024;
#pragma unroll
    for (int t = 0; t < 24; ++t)
        afr[t] = *(const short8*)(abase + t * 2048);

    float rs[16];
#pragma unroll
    for (int r = 0; r < 16; ++r) rs[r] = 0.f;

    const int ct0 = (blockIdx.x & 7) * 8;   // per-XCD stagger
    for (int it = 0; it < 64; ++it) {
        const int ct = blockIdx.y * 64 + ((ct0 + it) & 63);
        __syncthreads();   // prior tile's LDS reads complete
        stage_tile_async((const char*)cbs + (size_t)ct * TILE_BYTES, (char*)bs, wave, lane);
        __syncthreads();   // drains vmcnt(0): staged tile visible

        floatx16 acc;
#pragma unroll
        for (int r = 0; r < 16; ++r) acc[r] = 0.f;
        const char* bbase = (const char*)bs + (wn * 32 + l31) * 16 + half * 1024;
#pragma unroll
        for (int t = 0; t < 24; ++t) {
            const short8 bfr = *(const short8*)(bbase + t * 2048);
            acc = __builtin_amdgcn_mfma_f32_32x32x16_bf16(afr[t], bfr, acc, 0, 0, 0);
        }
#pragma unroll
        for (int r = 0; r < 16; ++r) rs[r] += __expf(acc[r] * INV_T);
    }

    // Reduce over the 32 col-lanes of each half; lanes 0/32 own the row partial.
#pragma unroll
    for (int r = 0; r < 16; ++r) {
        float s = rs[r];
#pragma unroll
        for (int off = 1; off < 32; off <<= 1) s += __shfl_xor(s, off, 64);
        if (l31 == 0) {
            const int rowl = (r & 3) + 8 * (r >> 2) + 4 * half;
            atomicAdd(&cent_sum[blockIdx.x * 64 + wm * 32 + rowl], s);
        }
    }
}

// ---------------------------------------------------------------------------
// Kernel 3: per-feature-row max+argmax over all K centroids. 512 blocks x 64 rows.
// ---------------------------------------------------------------------------
__global__ __launch_bounds__(256, 3) void rowmax_k(const float* __restrict__ f,
                                                   const unsigned short* __restrict__ cbs,
                                                   float* __restrict__ row_max,
                                                   int* __restrict__ row_arg) {
    __shared__ unsigned short bs[64 * D];   // 48 KB, chunk-column layout
    const int tid = threadIdx.x, lane = tid & 63, wave = tid >> 6;
    const int wm = wave >> 1, wn = wave & 1;
    const int l31 = lane & 31, half = lane >> 5;

    // Resident A: 32 feature rows, fp32->bf16 in-register (used by this block only).
    short8 afr[24];
    const float* arow = f + ((size_t)blockIdx.x * 64 + wm * 32 + l31) * D;
#pragma unroll
    for (int t = 0; t < 24; ++t) {
        const int k0 = t * 16 + half * 8;
        const float4 x = *(const float4*)(arow + k0);
        const float4 y = *(const float4*)(arow + k0 + 4);
        short8 a;
        a[0] = (short)f2bf(x.x); a[1] = (short)f2bf(x.y);
        a[2] = (short)f2bf(x.z); a[3] = (short)f2bf(x.w);
        a[4] = (short)f2bf(y.x); a[5] = (short)f2bf(y.y);
        a[6] = (short)f2bf(y.z); a[7] = (short)f2bf(y.w);
        afr[t] = a;
    }

    float bestv[16];
    int   besti[16];
#pragma unroll
    for (int r = 0; r < 16; ++r) { bestv[r] = -INFINITY; besti[r] = 0; }

    const int ct0 = (blockIdx.x & 7) * 16;  // per-XCD stagger
    for (int it = 0; it < K / 64; ++it) {
        const int ct = (ct0 + it) & (K / 64 - 1);
        __syncthreads();
        stage_tile_async((const char*)cbs + (size_t)ct * TILE_BYTES, (char*)bs, wave, lane);
        __syncthreads();

        floatx16 acc;
#pragma unroll
        for (int r = 0; r < 16; ++r) acc[r] = 0.f;
        const char* bbase = (const char*)bs + (wn * 32 + l31) * 16 + half * 1024;
#pragma unroll
        for (int t = 0; t < 24; ++t) {
            const short8 bfr = *(const short8*)(bbase + t * 2048);
            acc = __builtin_amdgcn_mfma_f32_32x32x16_bf16(afr[t], bfr, acc, 0, 0, 0);
        }
        const int curCol = ct * 64 + wn * 32 + l31;
#pragma unroll
        for (int r = 0; r < 16; ++r) {
            const float v = acc[r];
            if (v > bestv[r]) { bestv[r] = v; besti[r] = curCol; }
        }
    }

    // Cross-lane (col) reduce with low-index tie-break; halves are distinct rows.
#pragma unroll
    for (int r = 0; r < 16; ++r) {
        float v = bestv[r]; int ix = besti[r];
#pragma unroll
        for (int off = 1; off < 32; off <<= 1) {
            const float ov = __shfl_xor(v, off, 64);
            const int   oi = __shfl_xor(ix, off, 64);
            if (ov > v || (ov == v && oi < ix)) { v = ov; ix = oi; }
        }
        bestv[r] = v; besti[r] = ix;
    }

    __syncthreads();  // done with bs as a tile; reuse for cross-wave reduce
    float* rv = (float*)bs;        // [64][2]
    int*   ri = (int*)bs + 128;    // [64][2]
    if (l31 == 0) {
#pragma unroll
        for (int r = 0; r < 16; ++r) {
            const int rowl = wm * 32 + (r & 3) + 8 * (r >> 2) + 4 * half;
            rv[rowl * 2 + wn] = bestv[r];
            ri[rowl * 2 + wn] = besti[r];
        }
    }
    __syncthreads();
    if (tid < 64) {
        const float v0 = rv[tid * 2], v1 = rv[tid * 2 + 1];
        const int   i0 = ri[tid * 2], i1 = ri[tid * 2 + 1];
        const bool take1 = (v1 > v0) || (v1 == v0 && i1 < i0);
        row_max[blockIdx.x * 64 + tid] = take1 ? v1 : v0;
        row_arg[blockIdx.x * 64 + tid] = take1 ? i1 : i0;
    }
}

// ---------------------------------------------------------------------------
// Kernel 4: loss = mean_b log1p(cent_sum[arg_b] * exp(-max_b / T)).
// 64 blocks, per-block partial -> atomicAdd (out pre-zeroed by memsetAsync).
// ---------------------------------------------------------------------------
__global__ __launch_bounds__(256) void loss_k(const float* __restrict__ row_max,
                                              const int* __restrict__ row_arg,
                                              const float* __restrict__ cent_sum,
                                              float* __restrict__ out) {
    __shared__ float red[256];
    const int tid = threadIdx.x;
    float s = 0.f;
    for (int b = blockIdx.x * 256 + tid; b < B; b += gridDim.x * 256) {
        const float m = row_max[b];
        const float cs = cent_sum[row_arg[b]];
        s += log1pf(cs * expf(-m * INV_T));
    }
    red[tid] = s;
    __syncthreads();
    for (int off = 128; off > 0; off >>= 1) {
        if (tid < off) red[tid] += red[tid + off];
        __syncthreads();
    }
    if (tid == 0) atomicAdd(out, red[0] / (float)B);
}

extern "C" void kernel_launch(void* const* d_in, const int* in_sizes, int n_in,
                              void* d_out, int out_size, void* d_ws, size_t ws_size,
                              hipStream_t stream) {
    const float* features  = (const float*)d_in[0];   // [B, D] fp32
    const float* centroids = (const float*)d_in[1];   // [K, D] fp32
    float* out = (float*)d_out;

    char* ws = (char*)d_ws;
    unsigned short* cbs = (unsigned short*)ws;                      // swizzled bf16, 6.3 MB
    float* cent_sum = (float*)(ws + (size_t)(K / 64) * TILE_BYTES);
    float* row_max  = cent_sum + K;
    int*   row_arg  = (int*)(row_max + B);

    hipMemsetAsync(cent_sum, 0, K * sizeof(float), stream);
    hipMemsetAsync(out, 0, sizeof(float), stream);
    normalize_k<<<K, 64, 0, stream>>>(centroids, cbs);
    centsum_k<<<dim3(K / 64, 2), 256, 0, stream>>>(cbs, cent_sum);
    rowmax_k<<<B / 64, 256, 0, stream>>>(features, cbs, row_max, row_arg);
    loss_k<<<64, 256, 0, stream>>>(row_max, row_arg, cent_sum, out);
}

// Round 5
// 278.554 us; speedup vs baseline: 16.2833x; 1.5352x over previous
//
#include <hip/hip_runtime.h>
#include <math.h>

// B=32768 features, K=8192 centroids, D=384. All fixed by setup_inputs.
constexpr int B = 32768;
constexpr int K = 8192;
constexpr int D = 384;
constexpr float INV_T = 1.0f / 0.07f;

// Swizzled fp8 centroid buffer: per 64-row tile t (128 tiles):
// 16-B granule c (0..23) of row r (0..63) at cbs + t*24576 + (c*64 + r)*16.
// Byte-identical to the LDS tile layout -> staging is a straight coalesced
// copy (1 KB/instruction) and fragment addressing is shared.
constexpr int TILE_B = 24 * 64 * 16;   // 24576

typedef int    int8v    __attribute__((ext_vector_type(8)));
typedef float  floatx16 __attribute__((ext_vector_type(16)));

// ---------------------------------------------------------------------------
// Kernel 1: L2-normalize centroids -> fp8 e4m3, written in swizzled layout.
// One wave per row; lanes 0..47 each convert 8 elements (half a granule).
// ---------------------------------------------------------------------------
__global__ __launch_bounds__(64) void normalize_k(const float* __restrict__ cent,
                                                  unsigned char* __restrict__ cbs) {
    const int row = blockIdx.x, lane = threadIdx.x;
    const float* src = cent + (size_t)row * D;
    float4 x = {0.f, 0.f, 0.f, 0.f}, y = {0.f, 0.f, 0.f, 0.f};
    if (lane < 48) {
        x = *(const float4*)(src + lane * 8);
        y = *(const float4*)(src + lane * 8 + 4);
    }
    float ss = x.x * x.x + x.y * x.y + x.z * x.z + x.w * x.w
             + y.x * y.x + y.y * y.y + y.z * y.z + y.w * y.w;
#pragma unroll
    for (int off = 32; off > 0; off >>= 1) ss += __shfl_down(ss, off, 64);
    ss = __shfl(ss, 0, 64);
    const float inv = 1.0f / fmaxf(sqrtf(ss), 1e-12f);
    if (lane < 48) {
        int w0 = __builtin_amdgcn_cvt_pk_fp8_f32(x.x * inv, x.y * inv, 0, false);
        w0 = __builtin_amdgcn_cvt_pk_fp8_f32(x.z * inv, x.w * inv, w0, true);
        int w1 = __builtin_amdgcn_cvt_pk_fp8_f32(y.x * inv, y.y * inv, 0, false);
        w1 = __builtin_amdgcn_cvt_pk_fp8_f32(y.z * inv, y.w * inv, w1, true);
        char* dst = (char*)cbs + (size_t)(row >> 6) * TILE_B
                  + ((size_t)(lane >> 1) * 64 + (row & 63)) * 16 + (lane & 1) * 8;
        *(int2*)dst = make_int2(w0, w1);
    }
}

// ---------------------------------------------------------------------------
// Async staging of one swizzled 24KB fp8 tile into LDS: wave w copies bytes
// [w*6KB, (w+1)*6KB), 1KB (64 lanes x 16B contiguous) per instruction.
// ---------------------------------------------------------------------------
__device__ __forceinline__ void stage_tile_async(const char* __restrict__ gtile,
                                                 char* __restrict__ bs,
                                                 int wave, int lane) {
    const char* g = gtile + wave * 6144 + lane * 16;
    char* l = bs + wave * 6144;
#pragma unroll
    for (int i = 0; i < 6; ++i) {
        __builtin_amdgcn_global_load_lds(
            (const __attribute__((address_space(1))) unsigned int*)(g + i * 1024),
            (__attribute__((address_space(3))) unsigned int*)(l + i * 1024),
            16, 0, 0);
    }
}

// Fragment addressing (global swizzled or LDS tile):
// frag t (t=0..5 covers K=384), K-half h, row r: granules 4t+2h and 4t+2h+1,
// i.e. bytes (g*64+r)*16 -- two contiguous-across-lanes uint4 reads.
__device__ __forceinline__ int8v read_frag(const char* base, int t, int half) {
    const uint4 b0 = *(const uint4*)(base + (4 * t + 2 * half) * 1024);
    const uint4 b1 = *(const uint4*)(base + (4 * t + 2 * half + 1) * 1024);
    int8v f;
    f[0] = b0.x; f[1] = b0.y; f[2] = b0.z; f[3] = b0.w;
    f[4] = b1.x; f[5] = b1.y; f[6] = b1.z; f[7] = b1.w;
    return f;
}

// ---------------------------------------------------------------------------
// Kernel 2: cent_sum[j] = sum_i exp(c_j . c_i / T)  (symmetric -> row sums).
// Grid (K/64, 2). Double-buffered LDS staging.
// ---------------------------------------------------------------------------
__global__ __launch_bounds__(256, 3) void centsum_k(const unsigned char* __restrict__ cbs,
                                                    float* __restrict__ cent_sum) {
    __shared__ char bs[2][TILE_B];   // 48 KB
    const int tid = threadIdx.x, lane = tid & 63, wave = tid >> 6;
    const int wm = wave >> 1, wn = wave & 1;
    const int l31 = lane & 31, half = lane >> 5;

    // Resident A: this wave's 32 centroid rows from the swizzled fp8 buffer.
    int8v afr[6];
    const char* abase = (const char*)cbs + (size_t)blockIdx.x * TILE_B
                      + (wm * 32 + l31) * 16;
#pragma unroll
    for (int t = 0; t < 6; ++t) afr[t] = read_frag(abase, t, half);

    float rs[16];
#pragma unroll
    for (int r = 0; r < 16; ++r) rs[r] = 0.f;

    const int ct0 = (blockIdx.x & 7) * 8;   // per-XCD stagger
    auto tile_of = [&](int it) { return blockIdx.y * 64 + ((ct0 + it) & 63); };

    stage_tile_async((const char*)cbs + (size_t)tile_of(0) * TILE_B, bs[0], wave, lane);
    int cur = 0;
    for (int it = 0; it < 64; ++it) {
        __syncthreads();   // drains staging of bs[cur] + prior reads of bs[cur^1]
        if (it + 1 < 64)
            stage_tile_async((const char*)cbs + (size_t)tile_of(it + 1) * TILE_B,
                             bs[cur ^ 1], wave, lane);
        floatx16 acc;
#pragma unroll
        for (int r = 0; r < 16; ++r) acc[r] = 0.f;
        const char* bbase = bs[cur] + (wn * 32 + l31) * 16;
#pragma unroll
        for (int t = 0; t < 6; ++t) {
            const int8v bfr = read_frag(bbase, t, half);
            acc = __builtin_amdgcn_mfma_scale_f32_32x32x64_f8f6f4(
                      afr[t], bfr, acc, 0, 0, 0, 127, 0, 127);
        }
#pragma unroll
        for (int r = 0; r < 16; ++r) rs[r] += __expf(acc[r] * INV_T);
        cur ^= 1;
    }

    // Reduce over the 32 col-lanes of each half; lanes 0/32 own the row partial.
#pragma unroll
    for (int r = 0; r < 16; ++r) {
        float s = rs[r];
#pragma unroll
        for (int off = 1; off < 32; off <<= 1) s += __shfl_xor(s, off, 64);
        if (l31 == 0) {
            const int rowl = (r & 3) + 8 * (r >> 2) + 4 * half;
            atomicAdd(&cent_sum[blockIdx.x * 64 + wm * 32 + rowl], s);
        }
    }
}

// ---------------------------------------------------------------------------
// Kernel 3: per-feature-row max+argmax over all K centroids. 512 blocks x 64 rows.
// ---------------------------------------------------------------------------
__global__ __launch_bounds__(256, 3) void rowmax_k(const float* __restrict__ f,
                                                   const unsigned char* __restrict__ cbs,
                                                   float* __restrict__ row_max,
                                                   int* __restrict__ row_arg) {
    __shared__ char bs[2][TILE_B];   // 48 KB
    const int tid = threadIdx.x, lane = tid & 63, wave = tid >> 6;
    const int wm = wave >> 1, wn = wave & 1;
    const int l31 = lane & 31, half = lane >> 5;

    // Resident A: 32 feature rows, fp32 -> fp8 in-register.
    // Frag t, K-half h: elements k = 2h*32? no: k0 = half*32 + t*64 (+0..31).
    int8v afr[6];
    const float* arow = f + ((size_t)blockIdx.x * 64 + wm * 32 + l31) * D;
#pragma unroll
    for (int t = 0; t < 6; ++t) {
        const float* p = arow + t * 64 + half * 32;
        int8v a;
#pragma unroll
        for (int q = 0; q < 8; ++q) {
            const float4 v = *(const float4*)(p + q * 4);
            int w = __builtin_amdgcn_cvt_pk_fp8_f32(v.x, v.y, 0, false);
            w = __builtin_amdgcn_cvt_pk_fp8_f32(v.z, v.w, w, true);
            a[q] = w;
        }
        afr[t] = a;
    }

    float bestv[16];
    int   besti[16];
#pragma unroll
    for (int r = 0; r < 16; ++r) { bestv[r] = -INFINITY; besti[r] = 0; }

    const int ct0 = (blockIdx.x & 7) * 16;  // per-XCD stagger
    auto tile_of = [&](int it) { return (ct0 + it) & (K / 64 - 1); };

    stage_tile_async((const char*)cbs + (size_t)tile_of(0) * TILE_B, bs[0], wave, lane);
    int cur = 0;
    for (int it = 0; it < K / 64; ++it) {
        __syncthreads();
        if (it + 1 < K / 64)
            stage_tile_async((const char*)cbs + (size_t)tile_of(it + 1) * TILE_B,
                             bs[cur ^ 1], wave, lane);
        floatx16 acc;
#pragma unroll
        for (int r = 0; r < 16; ++r) acc[r] = 0.f;
        const char* bbase = bs[cur] + (wn * 32 + l31) * 16;
#pragma unroll
        for (int t = 0; t < 6; ++t) {
            const int8v bfr = read_frag(bbase, t, half);
            acc = __builtin_amdgcn_mfma_scale_f32_32x32x64_f8f6f4(
                      afr[t], bfr, acc, 0, 0, 0, 127, 0, 127);
        }
        const int curCol = tile_of(it) * 64 + wn * 32 + l31;
#pragma unroll
        for (int r = 0; r < 16; ++r) {
            const float v = acc[r];
            if (v > bestv[r]) { bestv[r] = v; besti[r] = curCol; }
        }
        cur ^= 1;
    }

    // Cross-lane (col) reduce with low-index tie-break; halves are distinct rows.
#pragma unroll
    for (int r = 0; r < 16; ++r) {
        float v = bestv[r]; int ix = besti[r];
#pragma unroll
        for (int off = 1; off < 32; off <<= 1) {
            const float ov = __shfl_xor(v, off, 64);
            const int   oi = __shfl_xor(ix, off, 64);
            if (ov > v || (ov == v && oi < ix)) { v = ov; ix = oi; }
        }
        bestv[r] = v; besti[r] = ix;
    }

    __syncthreads();  // done with bs as tiles; reuse for cross-wave reduce
    float* rv = (float*)bs;        // [64][2]
    int*   ri = (int*)bs + 128;    // [64][2]
    if (l31 == 0) {
#pragma unroll
        for (int r = 0; r < 16; ++r) {
            const int rowl = wm * 32 + (r & 3) + 8 * (r >> 2) + 4 * half;
            rv[rowl * 2 + wn] = bestv[r];
            ri[rowl * 2 + wn] = besti[r];
        }
    }
    __syncthreads();
    if (tid < 64) {
        const float v0 = rv[tid * 2], v1 = rv[tid * 2 + 1];
        const int   i0 = ri[tid * 2], i1 = ri[tid * 2 + 1];
        const bool take1 = (v1 > v0) || (v1 == v0 && i1 < i0);
        row_max[blockIdx.x * 64 + tid] = take1 ? v1 : v0;
        row_arg[blockIdx.x * 64 + tid] = take1 ? i1 : i0;
    }
}

// ---------------------------------------------------------------------------
// Kernel 4: loss = mean_b log1p(cent_sum[arg_b] * exp(-max_b / T)).
// 64 blocks, per-block partial -> atomicAdd (out pre-zeroed by memsetAsync).
// ---------------------------------------------------------------------------
__global__ __launch_bounds__(256) void loss_k(const float* __restrict__ row_max,
                                              const int* __restrict__ row_arg,
                                              const float* __restrict__ cent_sum,
                                              float* __restrict__ out) {
    __shared__ float red[256];
    const int tid = threadIdx.x;
    float s = 0.f;
    for (int b = blockIdx.x * 256 + tid; b < B; b += gridDim.x * 256) {
        const float m = row_max[b];
        const float cs = cent_sum[row_arg[b]];
        s += log1pf(cs * expf(-m * INV_T));
    }
    red[tid] = s;
    __syncthreads();
    for (int off = 128; off > 0; off >>= 1) {
        if (tid < off) red[tid] += red[tid + off];
        __syncthreads();
    }
    if (tid == 0) atomicAdd(out, red[0] / (float)B);
}

extern "C" void kernel_launch(void* const* d_in, const int* in_sizes, int n_in,
                              void* d_out, int out_size, void* d_ws, size_t ws_size,
                              hipStream_t stream) {
    const float* features  = (const float*)d_in[0];   // [B, D] fp32
    const float* centroids = (const float*)d_in[1];   // [K, D] fp32
    float* out = (float*)d_out;

    char* ws = (char*)d_ws;
    unsigned char* cbs = (unsigned char*)ws;                  // swizzled fp8, 3.1 MB
    float* cent_sum = (float*)(ws + (size_t)(K / 64) * TILE_B);
    float* row_max  = cent_sum + K;
    int*   row_arg  = (int*)(row_max + B);

    hipMemsetAsync(cent_sum, 0, K * sizeof(float), stream);
    hipMemsetAsync(out, 0, sizeof(float), stream);
    normalize_k<<<K, 64, 0, stream>>>(centroids, cbs);
    centsum_k<<<dim3(K / 64, 2), 256, 0, stream>>>(cbs, cent_sum);
    rowmax_k<<<B / 64, 256, 0, stream>>>(features, cbs, row_max, row_arg);
    loss_k<<<64, 256, 0, stream>>>(row_max, row_arg, cent_sum, out);
}

// Round 6
// 235.444 us; speedup vs baseline: 19.2648x; 1.1831x over previous
//
#include <hip/hip_runtime.h>
#include <math.h>

// B=32768 features, K=8192 centroids, D=384. All fixed by setup_inputs.
constexpr int B = 32768;
constexpr int K = 8192;
constexpr int D = 384;
constexpr float INV_T = 1.0f / 0.07f;

// Swizzled fp8 centroid buffer: per 64-row tile t (128 tiles):
// 16-B granule c (0..23) of row r (0..63) at cbs + t*24576 + (c*64 + r)*16.
// Byte-identical to the LDS tile layout.
constexpr int TILE_B = 24 * 64 * 16;   // 24576

typedef int    int8v    __attribute__((ext_vector_type(8)));
typedef float  floatx16 __attribute__((ext_vector_type(16)));

// ---------------------------------------------------------------------------
// Kernel 1: L2-normalize centroids -> fp8 e4m3, written in swizzled layout.
// ---------------------------------------------------------------------------
__global__ __launch_bounds__(64) void normalize_k(const float* __restrict__ cent,
                                                  unsigned char* __restrict__ cbs) {
    const int row = blockIdx.x, lane = threadIdx.x;
    const float* src = cent + (size_t)row * D;
    float4 x = {0.f, 0.f, 0.f, 0.f}, y = {0.f, 0.f, 0.f, 0.f};
    if (lane < 48) {
        x = *(const float4*)(src + lane * 8);
        y = *(const float4*)(src + lane * 8 + 4);
    }
    float ss = x.x * x.x + x.y * x.y + x.z * x.z + x.w * x.w
             + y.x * y.x + y.y * y.y + y.z * y.z + y.w * y.w;
#pragma unroll
    for (int off = 32; off > 0; off >>= 1) ss += __shfl_down(ss, off, 64);
    ss = __shfl(ss, 0, 64);
    const float inv = 1.0f / fmaxf(sqrtf(ss), 1e-12f);
    if (lane < 48) {
        int w0 = __builtin_amdgcn_cvt_pk_fp8_f32(x.x * inv, x.y * inv, 0, false);
        w0 = __builtin_amdgcn_cvt_pk_fp8_f32(x.z * inv, x.w * inv, w0, true);
        int w1 = __builtin_amdgcn_cvt_pk_fp8_f32(y.x * inv, y.y * inv, 0, false);
        w1 = __builtin_amdgcn_cvt_pk_fp8_f32(y.z * inv, y.w * inv, w1, true);
        char* dst = (char*)cbs + (size_t)(row >> 6) * TILE_B
                  + ((size_t)(lane >> 1) * 64 + (row & 63)) * 16 + (lane & 1) * 8;
        *(int2*)dst = make_int2(w0, w1);
    }
}

// ---------------------------------------------------------------------------
// Async staging of one swizzled 24KB fp8 tile into LDS (1 KB/instruction).
// ---------------------------------------------------------------------------
__device__ __forceinline__ void stage_tile_async(const char* __restrict__ gtile,
                                                 char* __restrict__ bs,
                                                 int wave, int lane) {
    const char* g = gtile + wave * 6144 + lane * 16;
    char* l = bs + wave * 6144;
#pragma unroll
    for (int i = 0; i < 6; ++i) {
        __builtin_amdgcn_global_load_lds(
            (const __attribute__((address_space(1))) unsigned int*)(g + i * 1024),
            (__attribute__((address_space(3))) unsigned int*)(l + i * 1024),
            16, 0, 0);
    }
}

// Fragment: frag t (0..5), K-half h, row r -> granules 4t+2h, 4t+2h+1.
__device__ __forceinline__ int8v read_frag(const char* base, int t, int half) {
    const uint4 b0 = *(const uint4*)(base + (4 * t + 2 * half) * 1024);
    const uint4 b1 = *(const uint4*)(base + (4 * t + 2 * half + 1) * 1024);
    int8v f;
    f[0] = b0.x; f[1] = b0.y; f[2] = b0.z; f[3] = b0.w;
    f[4] = b1.x; f[5] = b1.y; f[6] = b1.z; f[7] = b1.w;
    return f;
}

// ---------------------------------------------------------------------------
// Kernel 2: cent_sum[j] = sum_i exp(c_j . c_i / T).
// Block = 128 centroid rows x 1024-col slice (16 tiles). Grid 64 x 8 = 512.
// Each wave: 64 rows (2 A-sets in regs) x 32 cols; one B-frag read feeds
// two MFMA chains -> stage traffic halves vs R5.
// ---------------------------------------------------------------------------
__global__ __launch_bounds__(256, 2) void centsum_k(const unsigned char* __restrict__ cbs,
                                                    float* __restrict__ cent_sum) {
    __shared__ char bs[2][TILE_B];   // 48 KB double buffer
    const int tid = threadIdx.x, lane = tid & 63, wave = tid >> 6;
    const int wm = wave >> 1, wn = wave & 1;
    const int l31 = lane & 31, half = lane >> 5;
    const int rb = blockIdx.x >> 3, ch = blockIdx.x & 7;

    const int stag = (rb & 3) * 4;
    auto tile_of = [&](int it) { return ch * 16 + ((stag + it) & 15); };

    stage_tile_async((const char*)cbs + (size_t)tile_of(0) * TILE_B, bs[0], wave, lane);

    // A: 64 centroid rows (2 sets of 32) from the swizzled buffer.
    int8v afr[2][6];
#pragma unroll
    for (int s = 0; s < 2; ++s) {
        const char* abase = (const char*)cbs + (size_t)(rb * 2 + wm) * TILE_B
                          + (s * 32 + l31) * 16;
#pragma unroll
        for (int t = 0; t < 6; ++t) afr[s][t] = read_frag(abase, t, half);
    }

    float rs[2][16];
#pragma unroll
    for (int s = 0; s < 2; ++s)
#pragma unroll
        for (int r = 0; r < 16; ++r) rs[s][r] = 0.f;

    int cur = 0;
    for (int it = 0; it < 16; ++it) {
        __syncthreads();   // drains staging of bs[cur] + prior reads of bs[cur^1]
        if (it + 1 < 16)
            stage_tile_async((const char*)cbs + (size_t)tile_of(it + 1) * TILE_B,
                             bs[cur ^ 1], wave, lane);
        floatx16 acc0, acc1;
#pragma unroll
        for (int r = 0; r < 16; ++r) { acc0[r] = 0.f; acc1[r] = 0.f; }
        const char* bbase = bs[cur] + (wn * 32 + l31) * 16;
#pragma unroll
        for (int t = 0; t < 6; ++t) {
            const int8v bfr = read_frag(bbase, t, half);
            acc0 = __builtin_amdgcn_mfma_scale_f32_32x32x64_f8f6f4(
                       afr[0][t], bfr, acc0, 0, 0, 0, 127, 0, 127);
            acc1 = __builtin_amdgcn_mfma_scale_f32_32x32x64_f8f6f4(
                       afr[1][t], bfr, acc1, 0, 0, 0, 127, 0, 127);
        }
#pragma unroll
        for (int r = 0; r < 16; ++r) {
            rs[0][r] += __expf(acc0[r] * INV_T);
            rs[1][r] += __expf(acc1[r] * INV_T);
        }
        cur ^= 1;
    }

    // Reduce over 32 col-lanes per half; lanes 0/32 own the row partial.
#pragma unroll
    for (int s = 0; s < 2; ++s)
#pragma unroll
        for (int r = 0; r < 16; ++r) {
            float v = rs[s][r];
#pragma unroll
            for (int off = 1; off < 32; off <<= 1) v += __shfl_xor(v, off, 64);
            if (l31 == 0) {
                const int rowl = (r & 3) + 8 * (r >> 2) + 4 * half;
                atomicAdd(&cent_sum[rb * 128 + wm * 64 + s * 32 + rowl], v);
            }
        }
}

// ---------------------------------------------------------------------------
// Kernel 3: per-feature-row max+argmax. Block = 128 rows x 4096-col half
// (64 tiles). Grid B/128 x 2 = 512 blocks, 2/CU. Wave = 64 rows x 32 cols.
// Output per (row, col-half); merged in loss_k.
// ---------------------------------------------------------------------------
__global__ __launch_bounds__(256, 2) void rowmax_k(const float* __restrict__ f,
                                                   const unsigned char* __restrict__ cbs,
                                                   float* __restrict__ row_max2,
                                                   int* __restrict__ row_arg2) {
    __shared__ char bs[2][TILE_B];   // 48 KB double buffer
    const int tid = threadIdx.x, lane = tid & 63, wave = tid >> 6;
    const int wm = wave >> 1, wn = wave & 1;
    const int l31 = lane & 31, half = lane >> 5;
    const int rb = blockIdx.x >> 1, ch = blockIdx.x & 1;

    const int stag = (rb & 7) * 8;
    auto tile_of = [&](int it) { return ch * 64 + ((stag + it) & 63); };

    stage_tile_async((const char*)cbs + (size_t)tile_of(0) * TILE_B, bs[0], wave, lane);

    // A: 64 feature rows (2 sets of 32), fp32 -> fp8 in-register.
    int8v afr[2][6];
    const int rowbase = rb * 128 + wm * 64;
#pragma unroll
    for (int s = 0; s < 2; ++s) {
        const float* arow = f + (size_t)(rowbase + s * 32 + l31) * D;
#pragma unroll
        for (int t = 0; t < 6; ++t) {
            const float* p = arow + t * 64 + half * 32;
            int8v a;
#pragma unroll
            for (int q = 0; q < 8; ++q) {
                const float4 v = *(const float4*)(p + q * 4);
                int w = __builtin_amdgcn_cvt_pk_fp8_f32(v.x, v.y, 0, false);
                w = __builtin_amdgcn_cvt_pk_fp8_f32(v.z, v.w, w, true);
                a[q] = w;
            }
            afr[s][t] = a;
        }
    }

    float bv[2][16];
    int   bi[2][16];
#pragma unroll
    for (int s = 0; s < 2; ++s)
#pragma unroll
        for (int r = 0; r < 16; ++r) { bv[s][r] = -INFINITY; bi[s][r] = 0; }

    int cur = 0;
    for (int it = 0; it < 64; ++it) {
        __syncthreads();
        if (it + 1 < 64)
            stage_tile_async((const char*)cbs + (size_t)tile_of(it + 1) * TILE_B,
                             bs[cur ^ 1], wave, lane);
        floatx16 acc0, acc1;
#pragma unroll
        for (int r = 0; r < 16; ++r) { acc0[r] = 0.f; acc1[r] = 0.f; }
        const char* bbase = bs[cur] + (wn * 32 + l31) * 16;
#pragma unroll
        for (int t = 0; t < 6; ++t) {
            const int8v bfr = read_frag(bbase, t, half);
            acc0 = __builtin_amdgcn_mfma_scale_f32_32x32x64_f8f6f4(
                       afr[0][t], bfr, acc0, 0, 0, 0, 127, 0, 127);
            acc1 = __builtin_amdgcn_mfma_scale_f32_32x32x64_f8f6f4(
                       afr[1][t], bfr, acc1, 0, 0, 0, 127, 0, 127);
        }
        const int curCol = tile_of(it) * 64 + wn * 32 + l31;
#pragma unroll
        for (int r = 0; r < 16; ++r) {
            if (acc0[r] > bv[0][r]) { bv[0][r] = acc0[r]; bi[0][r] = curCol; }
            if (acc1[r] > bv[1][r]) { bv[1][r] = acc1[r]; bi[1][r] = curCol; }
        }
        cur ^= 1;
    }

    // Cross-lane (col) reduce with low-index tie-break.
#pragma unroll
    for (int s = 0; s < 2; ++s)
#pragma unroll
        for (int r = 0; r < 16; ++r) {
            float v = bv[s][r]; int ix = bi[s][r];
#pragma unroll
            for (int off = 1; off < 32; off <<= 1) {
                const float ov = __shfl_xor(v, off, 64);
                const int   oi = __shfl_xor(ix, off, 64);
                if (ov > v || (ov == v && oi < ix)) { v = ov; ix = oi; }
            }
            bv[s][r] = v; bi[s][r] = ix;
        }

    __syncthreads();  // done with tiles; reuse LDS for cross-wave (wn) merge
    float* rv = (float*)bs;          // [128][2]
    int*   ri = (int*)bs + 256;      // [128][2]
    if (l31 == 0) {
#pragma unroll
        for (int s = 0; s < 2; ++s)
#pragma unroll
            for (int r = 0; r < 16; ++r) {
                const int row = wm * 64 + s * 32 + (r & 3) + 8 * (r >> 2) + 4 * half;
                rv[row * 2 + wn] = bv[s][r];
                ri[row * 2 + wn] = bi[s][r];
            }
    }
    __syncthreads();
    if (tid < 128) {
        const float v0 = rv[tid * 2], v1 = rv[tid * 2 + 1];
        const int   i0 = ri[tid * 2], i1 = ri[tid * 2 + 1];
        const bool take1 = (v1 > v0) || (v1 == v0 && i1 < i0);
        row_max2[(size_t)(rb * 128 + tid) * 2 + ch] = take1 ? v1 : v0;
        row_arg2[(size_t)(rb * 128 + tid) * 2 + ch] = take1 ? i1 : i0;
    }
}

// ---------------------------------------------------------------------------
// Kernel 4: merge col-halves, loss = mean_b log1p(cent_sum[arg]*exp(-max/T)).
// ---------------------------------------------------------------------------
__global__ __launch_bounds__(256) void loss_k(const float* __restrict__ row_max2,
                                              const int* __restrict__ row_arg2,
                                              const float* __restrict__ cent_sum,
                                              float* __restrict__ out) {
    __shared__ float red[256];
    const int tid = threadIdx.x;
    float s = 0.f;
    for (int b = blockIdx.x * 256 + tid; b < B; b += gridDim.x * 256) {
        const float m0 = row_max2[(size_t)b * 2], m1 = row_max2[(size_t)b * 2 + 1];
        // half 0 holds cols 0..4095 < half 1's: ties -> half 0.
        const bool take1 = m1 > m0;
        const float m = take1 ? m1 : m0;
        const int ix = row_arg2[(size_t)b * 2 + (take1 ? 1 : 0)];
        s += log1pf(cent_sum[ix] * expf(-m * INV_T));
    }
    red[tid] = s;
    __syncthreads();
    for (int off = 128; off > 0; off >>= 1) {
        if (tid < off) red[tid] += red[tid + off];
        __syncthreads();
    }
    if (tid == 0) atomicAdd(out, red[0] / (float)B);
}

extern "C" void kernel_launch(void* const* d_in, const int* in_sizes, int n_in,
                              void* d_out, int out_size, void* d_ws, size_t ws_size,
                              hipStream_t stream) {
    const float* features  = (const float*)d_in[0];   // [B, D] fp32
    const float* centroids = (const float*)d_in[1];   // [K, D] fp32
    float* out = (float*)d_out;

    char* ws = (char*)d_ws;
    unsigned char* cbs = (unsigned char*)ws;                  // swizzled fp8, 3.1 MB
    float* cent_sum = (float*)(ws + (size_t)(K / 64) * TILE_B);
    float* row_max2 = cent_sum + K;                           // [B][2]
    int*   row_arg2 = (int*)(row_max2 + 2 * B);               // [B][2]

    hipMemsetAsync(cent_sum, 0, K * sizeof(float), stream);
    hipMemsetAsync(out, 0, sizeof(float), stream);
    normalize_k<<<K, 64, 0, stream>>>(centroids, cbs);
    centsum_k<<<(K / 128) * 8, 256, 0, stream>>>(cbs, cent_sum);
    rowmax_k<<<(B / 128) * 2, 256, 0, stream>>>(features, cbs, row_max2, row_arg2);
    loss_k<<<64, 256, 0, stream>>>(row_max2, row_arg2, cent_sum, out);
}